// Round 3
// baseline (18.418 us; speedup 1.0000x reference)
//
#include <hip/hip_runtime.h>
#include <hip/hip_bf16.h>

#define NEGV (-9e15f)

__device__ __forceinline__ float wsum(float v) {
#pragma unroll
    for (int off = 32; off > 0; off >>= 1) v += __shfl_xor(v, off, 64);
    return v;
}
__device__ __forceinline__ float wmax(float v) {
#pragma unroll
    for (int off = 32; off > 0; off >>= 1) v = fmaxf(v, __shfl_xor(v, off, 64));
    return v;
}

// Distinctive marker if host-side input-layout verification fails.
__global__ __launch_bounds__(64) void sentinel_kernel(float* __restrict__ out) {
    out[blockIdx.x * 64 + threadIdx.x] = 111222.0f;
}

// One wave (64 lanes) per (b,i) row. bs=8, N=512, Fx=8, F=64, D=16.
// All inputs f32 (established: round-1 bf16 read -> NaN; npz size matches f32).
// Output written as f32 this round (dtype experiment).
__global__ __launch_bounds__(64) void gat_fused_f32(
    const float* __restrict__ input, const int* __restrict__ adj,
    const float* __restrict__ ext, const float* __restrict__ side,
    const float* __restrict__ W, const float* __restrict__ a,
    const float* __restrict__ WS, const float* __restrict__ aS,
    const float* __restrict__ WQ, const float* __restrict__ WK,
    const float* __restrict__ WV, float* __restrict__ out)
{
    const int N = 512, F = 64;
    const int lane = threadIdx.x;
    const int bi = blockIdx.x;
    const int b = bi >> 9;
    const int i = bi & (N - 1);

    // ---- adj dtype probe (int32 vs int64), wave-uniform, data-deterministic.
    // If adj is int64 with values {0,1}, int32 words at odd indices 1..1023
    // (high words of the first 512 entries) are ALL zero. If int32, those
    // words are random 0/1 -> probability all-zero ~ 2^-256.
    int probe = 0;
#pragma unroll
    for (int t = 0; t < 8; t++) probe |= adj[2 * (lane * 8 + t) + 1];
    const bool adj64 = (__any(probe != 0) == 0);

    // ---- per-block scalar weight contractions (lane-parallel + butterfly) ----
    const float wf  = W[lane];
    const float wvf = WV[lane];
    const float c1  = wsum(wf * a[lane]);
    const float c2  = wsum(wf * a[F + lane]);
    const float wsf = WS[lane];
    const float cS1 = wsum(wsf * aS[lane]);
    const float cS2 = wsum(wsf * aS[F + lane]);
    float q0 = 0.f, q1 = 0.f, k0 = 0.f, k1 = 0.f;
    if (lane < 16) {
        q0 = WQ[lane]; q1 = WQ[16 + lane];
        k0 = WK[lane]; k1 = WK[16 + lane];
    }
    const float a00 = wsum(q0 * k0);
    const float a01 = wsum(q0 * k1);
    const float a10 = wsum(q1 * k0);
    const float a11 = wsum(q1 * k1);

    const int row = b * N + i;
    const float x_i = input[row];
    const float y_i = side[row];

    float exti[8];
    {
        const float4 e0 = ((const float4*)(ext + row * 8))[0];
        const float4 e1 = ((const float4*)(ext + row * 8))[1];
        exti[0] = e0.x; exti[1] = e0.y; exti[2] = e0.z; exti[3] = e0.w;
        exti[4] = e1.x; exti[5] = e1.y; exti[6] = e1.z; exti[7] = e1.w;
    }

    const float s1i  = c1 * x_i;
    const float sS1i = cS1 * y_i;

    // ---- pass 1: attention logits over j, row softmax stats ----
    float L[8], xj[8];
#pragma unroll
    for (int t = 0; t < 8; t++) {
        const int j = lane + 64 * t;
        const float xv = input[b * N + j];
        const float yv = side[b * N + j];
        xj[t] = xv;
        float e  = s1i + c2 * xv;   e  = (e  > 0.f) ? e  : 0.2f * e;
        float es = sS1i + cS2 * yv; es = (es > 0.f) ? es : 0.2f * es;
        const float v = e + es;
        const int am = adj64 ? (adj[2 * (i * N + j)] | adj[2 * (i * N + j) + 1])
                             : adj[i * N + j];
        L[t] = (am != 0 && v > 0.f) ? v : NEGV;
    }
    float M = L[0];
#pragma unroll
    for (int t = 1; t < 8; t++) M = fmaxf(M, L[t]);
    M = wmax(M);
    float E[8]; float ssum = 0.f;
#pragma unroll
    for (int t = 0; t < 8; t++) { E[t] = __expf(L[t] - M); ssum += E[t]; }
    ssum = wsum(ssum);
    const float inv = 1.f / ssum;

    // ---- pass 2: A = sum_j att_j x_j ; R = sum_j att_j sum_f sm_f(dot) ext_i[f] ----
    float A = 0.f, Rp = 0.f;
#pragma unroll
    for (int t = 0; t < 8; t++) {
        const int j = lane + 64 * t;
        const float att = E[t] * inv;
        A += att * xj[t];
        const float qk0 = 0.25f * (x_i * a00 + xj[t] * a10);
        const float qk1 = 0.25f * (x_i * a01 + xj[t] * a11);

        float extj[8];
        {
            const float4 e0 = ((const float4*)(ext + (b * N + j) * 8))[0];
            const float4 e1 = ((const float4*)(ext + (b * N + j) * 8))[1];
            extj[0] = e0.x; extj[1] = e0.y; extj[2] = e0.z; extj[3] = e0.w;
            extj[4] = e1.x; extj[5] = e1.y; extj[6] = e1.z; extj[7] = e1.w;
        }

        float d[8]; float dm = NEGV;
#pragma unroll
        for (int f = 0; f < 8; f++) {
            float dv = exti[f] * qk0 + extj[f] * qk1;
            dv = (dv > 0.f) ? dv : NEGV;
            d[f] = dv;
            dm = fmaxf(dm, dv);
        }
        float dsum = 0.f;
#pragma unroll
        for (int f = 0; f < 8; f++) { d[f] = __expf(d[f] - dm); dsum += d[f]; }
        const float w = att / dsum;
#pragma unroll
        for (int f = 0; f < 8; f++) Rp += d[f] * w * exti[f];
    }
    A = wsum(A);
    const float R = wsum(Rp);

    // ---- epilogue: two elu'd rank-1 outputs, lane = feature ----
    float o0 = A * wf;
    o0 = (o0 > 0.f) ? o0 : expm1f(o0);
    float o1 = R * wvf;
    o1 = (o1 > 0.f) ? o1 : expm1f(o1);

    out[row * F + lane] = o0;
    out[8 * N * F + row * F + lane] = o1;
}

extern "C" void kernel_launch(void* const* d_in, const int* in_sizes, int n_in,
                              void* d_out, int out_size, void* d_ws, size_t ws_size,
                              hipStream_t stream) {
    // Verify input layout matches setup_inputs() dict order.
    static const int exp_sizes[11] = {4096, 262144, 32768, 4096, 64, 128, 64, 128, 32, 32, 64};
    bool ok = (n_in == 11) && (out_size == 524288);
    if (ok) {
        for (int k = 0; k < 11; k++) if (in_sizes[k] != exp_sizes[k]) ok = false;
    }
    if (!ok) {
        sentinel_kernel<<<4096, 64, 0, stream>>>((float*)d_out);
        return;
    }

    gat_fused_f32<<<8 * 512, 64, 0, stream>>>(
        (const float*)d_in[0], (const int*)d_in[1],
        (const float*)d_in[2], (const float*)d_in[3],
        (const float*)d_in[4], (const float*)d_in[5],
        (const float*)d_in[6], (const float*)d_in[7],
        (const float*)d_in[8], (const float*)d_in[9],
        (const float*)d_in[10],
        (float*)d_out);
}